// Round 17
// baseline (478.938 us; speedup 1.0000x reference)
//
#include <hip/hip_runtime.h>
#include <hip/hip_bf16.h>

using f32x4 = __attribute__((ext_vector_type(4))) float;
using s16x8 = __attribute__((ext_vector_type(8))) short;

#define DEVFN static __device__ __forceinline__

static constexpr int NCOL = 256;
static constexpr int MROWS = 8192;
static constexpr int BM = 256;            // full 256-wide C panel per block
static constexpr int KS = 8;              // split-K -> 32*8 = 256 blocks
static constexpr int NT = MROWS / BM;     // 32 row-tiles
static constexpr size_t PSLICE = (size_t)MROWS * NCOL;  // shorts per partial

DEVFN unsigned short f2bf(float f) {
  union { float f; unsigned u; } x; x.f = f;
  unsigned u = x.u;
  u += 0x7fffu + ((u >> 16) & 1u);   // RNE
  return (unsigned short)(u >> 16);
}

DEVFN float bf2f(unsigned short u) {
  union { unsigned u; float f; } x; x.u = (unsigned)u << 16; return x.f;
}

DEVFN s16x8 pack8(f32x4 v0, f32x4 v1) {
  union { s16x8 v; __hip_bfloat162 h[4]; } pk;
  pk.h[0] = __float22bfloat162_rn(float2{v0[0], v0[1]});
  pk.h[1] = __float22bfloat162_rn(float2{v0[2], v0[3]});
  pk.h[2] = __float22bfloat162_rn(float2{v1[0], v1[1]});
  pk.h[3] = __float22bfloat162_rn(float2{v1[2], v1[3]});
  return pk.v;
}

DEVFN void async16(void* lds, const void* g) {
  __builtin_amdgcn_global_load_lds((const __attribute__((address_space(1))) unsigned*)g,
                                   (__attribute__((address_space(3))) unsigned*)lds,
                                   16, 0, 0);
}

// AP8 A-format: per (256-row tile T, 32-k tile kt) a contiguous 16KB block at
// (T*KT + kt)*8192 shorts, KT = K/32; within, element (row,k) at
// (k>>3)*2048 + row*8 + (k&7).  A fragment (16 consecutive rows, one k-group)
// is 256B contiguous -> conflict-free ds_read_b128; staging is linear.
// B P8 format: elem(k,j) at ((k>>3)*256 + j)*8 + (k&7) (same property).

// C[M,256] = A[M,K] @ B[K,256].  BM=256, BK=32/step, 8 waves (wm2 x wn4),
// wave-tile 128x64, acc[8][4].  4-buffer LDS ring (128KB -> 1 block/CU),
// 3-deep prefetch with counted per-thread vmcnt; 2 raw barriers/step; never
// drains mid-loop.  Output: bf16 P8 partial slice kh.
__global__ __launch_bounds__(512, 2)
void gemm256(const unsigned short* __restrict__ Ap, int Kfull,
             const unsigned short* __restrict__ Bp8,
             unsigned short* __restrict__ Pout)
{
  __shared__ __align__(16) unsigned short As[4][8192];   // 4 x 16KB
  __shared__ __align__(16) unsigned short Bs[4][8192];   // 4 x 16KB -> 128KB

  const int nwg = NT * KS, q = nwg / 8;                  // q = 32 = one kh/XCD
  const int logical = (blockIdx.x & 7) * q + (blockIdx.x >> 3);
  const int kh = logical / NT;
  const int tile = logical % NT;
  const int klen = Kfull / KS;
  const int nt = klen / 32;
  const int k0 = kh * klen;
  const int KT = Kfull >> 5;
  const int kt0 = k0 >> 5;
  const int tid = threadIdx.x, lane = tid & 63;
  const int wm = (tid >> 6) >> 2;       // 0..1 : rows wm*128..+128
  const int wn = (tid >> 6) & 3;        // 0..3 : cols wn*64..+64
  const int lr = lane & 15, lg = lane >> 4;

  auto stage = [&](int buf, int t) {    // 4 async ops / thread, all linear
    const unsigned short* a = Ap + ((size_t)tile * KT + kt0 + t) * 8192 + tid * 8;
    async16(&As[buf][tid * 8], a);
    async16(&As[buf][4096 + tid * 8], a + 4096);
    const unsigned short* b = Bp8 + (size_t)(k0 + t * 32) * 256 + tid * 8;
    async16(&Bs[buf][tid * 8], b);
    async16(&Bs[buf][4096 + tid * 8], b + 4096);
  };

  f32x4 acc[8][4] = {};

  if (nt > 0) stage(0, 0);
  if (nt > 1) stage(1, 1);
  if (nt > 2) stage(2, 2);

  for (int t = 0; t < nt; ++t) {
    if (t + 3 < nt) stage((t + 3) & 3, t + 3);     // into buf freed at t-1
    const int rem = (nt - 1 - t) < 3 ? (nt - 1 - t) : 3;
    if (rem == 3)      asm volatile("s_waitcnt vmcnt(12)");  // t's 4 ops landed
    else if (rem == 2) asm volatile("s_waitcnt vmcnt(8)");
    else if (rem == 1) asm volatile("s_waitcnt vmcnt(4)");
    else               asm volatile("s_waitcnt vmcnt(0)");
    __builtin_amdgcn_s_barrier();                  // all waves' stage(t) landed
    __builtin_amdgcn_sched_barrier(0);             // pin LDS reads below
    const int cur = t & 3;
    s16x8 bfr[4];
#pragma unroll
    for (int fn = 0; fn < 4; ++fn)
      bfr[fn] = *(const s16x8*)&Bs[cur][lg * 2048 + (wn * 64 + fn * 16 + lr) * 8];
#pragma unroll
    for (int fm = 0; fm < 8; ++fm) {
      const int row = wm * 128 + fm * 16 + lr;
      s16x8 af = *(const s16x8*)&As[cur][lg * 2048 + row * 8];
#pragma unroll
      for (int fn = 0; fn < 4; ++fn)
        acc[fm][fn] = __builtin_amdgcn_mfma_f32_16x16x32_bf16(af, bfr[fn], acc[fm][fn], 0, 0, 0);
    }
    __builtin_amdgcn_s_barrier();                  // all waves done with buf cur
  }

  // C/D layout: col = lane&15, row = (lane>>4)*4 + reg.  Store bf16 P8.
  unsigned short* dst = Pout + (size_t)kh * PSLICE;
#pragma unroll
  for (int fm = 0; fm < 8; ++fm) {
    const int r0 = tile * BM + wm * 128 + fm * 16 + lg * 4;   // r0&7 in {0,4}
#pragma unroll
    for (int fn = 0; fn < 4; ++fn) {
      const int col = wn * 64 + fn * 16 + lr;
      ushort4 u;
      u.x = f2bf(acc[fm][fn][0]); u.y = f2bf(acc[fm][fn][1]);
      u.z = f2bf(acc[fm][fn][2]); u.w = f2bf(acc[fm][fn][3]);
      *(ushort4*)&dst[((size_t)(r0 >> 3) * 256 + col) * 8 + (r0 & 7)] = u;
    }
  }
}

// ---- stream conversion kernels -----------------------------------------

// f32 row-major [M][K] -> AP8 bf16.  Block = (T,kt), 1024 threads = (kc,row).
// Writes 16B coalesced; reads 16B strided but each 64B line is fully consumed
// within the block (kc pairs share lines -> L1/L2 reuse).
template<int KTSH>   // K = 32 << KTSH
__global__ void k_cvt_ap(const float* __restrict__ W, unsigned short* __restrict__ outp) {
  const int K = 32 << KTSH;
  const int bt = blockIdx.x;            // T*KT + kt
  const int kt = bt & ((1 << KTSH) - 1);
  const int T = bt >> KTSH;
  const int kc = threadIdx.x >> 8;      // 0..3
  const int row = threadIdx.x & 255;
  const float* p = W + ((size_t)T * 256 + row) * K + kt * 32 + kc * 8;
  s16x8 v = pack8(*(const f32x4*)p, *(const f32x4*)(p + 4));
  *(s16x8*)&outp[(size_t)bt * 8192 + kc * 2048 + row * 8] = v;
}

// f32 [K][256] -> P8 bf16 (weights)
__global__ void k_convert_p8(const float* __restrict__ W, int K,
                             unsigned short* __restrict__ outp) {
  int tid = blockIdx.x * blockDim.x + threadIdx.x;
  if (tid >= K * NCOL / 4) return;
  int j = tid & (NCOL - 1);
  int i0 = (tid >> 8) << 2;
  unsigned short u[4];
#pragma unroll
  for (int r = 0; r < 4; ++r) u[r] = f2bf(W[(size_t)(i0 + r) * NCOL + j]);
  size_t off = ((size_t)(i0 >> 3) * NCOL + j) * 8 + (i0 & 7);
  *(ushort4*)&outp[off] = make_ushort4(u[0], u[1], u[2], u[3]);
}

// sum 8 bf16-P8 partials.  One thread per (8-row group, col).
// MODE 0: P8 bf16 out (optional per-row filt); MODE 1: relu -> AP8 bf16
// (K=256); MODE 2: f32 row-major out.
template<int MODE>
__global__ void k_reduce(const unsigned short* __restrict__ P,
                         const float* __restrict__ filt, void* __restrict__ Out) {
  const int tid = blockIdx.x * blockDim.x + threadIdx.x;   // 262144 threads
  const int j = tid & 255;
  const int i8 = tid >> 8;
  const int i0 = i8 * 8;
  const size_t base = ((size_t)i8 * 256 + j) * 8;
  float f[8] = {};
#pragma unroll
  for (int h = 0; h < 8; ++h) {
    s16x8 pv = *(const s16x8*)&P[base + (size_t)h * PSLICE];
#pragma unroll
    for (int r = 0; r < 8; ++r) f[r] += bf2f((unsigned short)pv[r]);
  }
  if constexpr (MODE == 0) {
    if (filt) {
#pragma unroll
      for (int r = 0; r < 8; ++r) f[r] *= filt[i0 + r];
    }
    union { s16x8 v; unsigned short u[8]; } o;
#pragma unroll
    for (int r = 0; r < 8; ++r) o.u[r] = f2bf(f[r]);
    *(s16x8*)&((unsigned short*)Out)[base] = o.v;
  } else if constexpr (MODE == 1) {
    unsigned short* O = (unsigned short*)Out;
#pragma unroll
    for (int r = 0; r < 8; ++r) {
      const int row = i0 + r;
      // AP8, K=256 (KT=8): block (row>>8)*8 + (j>>5); elem (row&255, j&31)
      O[((size_t)(row >> 8) * 8 + (j >> 5)) * 8192 + ((j >> 3) & 3) * 2048
        + (row & 255) * 8 + (j & 7)] = f2bf(fmaxf(f[r], 0.f));
    }
  } else {
    float* O = (float*)Out;
#pragma unroll
    for (int r = 0; r < 8; ++r)
      O[(size_t)(i0 + r) * NCOL + j] = f[r];
  }
}

extern "C" void kernel_launch(void* const* d_in, const int* in_sizes, int n_in,
                              void* d_out, int out_size, void* d_ws, size_t ws_size,
                              hipStream_t stream) {
  const float* input = (const float*)d_in[0];
  const float* Wv    = (const float*)d_in[1];
  const float* Winv  = (const float*)d_in[2];
  const float* W1    = (const float*)d_in[3];
  const float* W2    = (const float*)d_in[4];
  const float* f1    = (const float*)d_in[5];
  const float* f2    = (const float*)d_in[6];
  float* out = (float*)d_out;

  char* ws = (char*)d_ws;
  unsigned short* WvB   = (unsigned short*)(ws);                 // 128MB AP8
  unsigned short* WinvB = (unsigned short*)(ws + 0x8000000);     // 128MB AP8
  unsigned short* inB   = (unsigned short*)(ws + 0x10000000);    // 8MB AP8
  unsigned short* partB = (unsigned short*)(ws + 0x10800000);    // 32MB (8 x bf16 P8)
  unsigned short* t1p   = (unsigned short*)(ws + 0x12800000);    // 4MB each, P8
  unsigned short* s1p   = (unsigned short*)(ws + 0x12C00000);
  unsigned short* t2p   = (unsigned short*)(ws + 0x13000000);
  unsigned short* s2p   = (unsigned short*)(ws + 0x13400000);
  unsigned short* h1b   = (unsigned short*)(ws + 0x13800000);    // 4MB AP8
  unsigned short* W1p   = (unsigned short*)(ws + 0x13C00000);    // 256KB
  unsigned short* W2p   = (unsigned short*)(ws + 0x13C40000);    // 128KB

  dim3 gemmG(NT * KS), gemmT(512);                     // 256 WGs, 1/CU
  dim3 cvT(1024);
  dim3 rT(256), rG(MROWS * NCOL / 8 / 256);            // 1024 WGs

  // stream converts
  k_cvt_ap<8><<<dim3(32 * 256), cvT, 0, stream>>>(Wv, WvB);
  k_cvt_ap<8><<<dim3(32 * 256), cvT, 0, stream>>>(Winv, WinvB);
  k_cvt_ap<4><<<dim3(32 * 16),  cvT, 0, stream>>>(input, inB);
  k_convert_p8<<<dim3(128), rT, 0, stream>>>(W1, 512, W1p);
  k_convert_p8<<<dim3(64),  rT, 0, stream>>>(W2, 256, W2p);

  // t1 = input @ W1
  gemm256<<<gemmG, gemmT, 0, stream>>>(inB, 512, W1p, partB);
  k_reduce<0><<<rG, rT, 0, stream>>>(partB, nullptr, t1p);
  // s1 = diag(f1).(Winv @ t1)
  gemm256<<<gemmG, gemmT, 0, stream>>>(WinvB, 8192, t1p, partB);
  k_reduce<0><<<rG, rT, 0, stream>>>(partB, f1, s1p);
  // h1 = relu(Wv @ s1) -> AP8
  gemm256<<<gemmG, gemmT, 0, stream>>>(WvB, 8192, s1p, partB);
  k_reduce<1><<<rG, rT, 0, stream>>>(partB, nullptr, h1b);
  // t2 = h1 @ W2
  gemm256<<<gemmG, gemmT, 0, stream>>>(h1b, 256, W2p, partB);
  k_reduce<0><<<rG, rT, 0, stream>>>(partB, nullptr, t2p);
  // s2 = diag(f2).(Winv @ t2)
  gemm256<<<gemmG, gemmT, 0, stream>>>(WinvB, 8192, t2p, partB);
  k_reduce<0><<<rG, rT, 0, stream>>>(partB, f2, s2p);
  // out = Wv @ s2
  gemm256<<<gemmG, gemmT, 0, stream>>>(WvB, 8192, s2p, partB);
  k_reduce<2><<<rG, rT, 0, stream>>>(partB, nullptr, out);
}

// Round 18
// 397.761 us; speedup vs baseline: 1.2041x; 1.2041x over previous
//
#include <hip/hip_runtime.h>
#include <hip/hip_bf16.h>

using f32x4 = __attribute__((ext_vector_type(4))) float;
using s16x8 = __attribute__((ext_vector_type(8))) short;

#define DEVFN static __device__ __forceinline__

static constexpr int NCOL = 256;
static constexpr int MROWS = 8192;
static constexpr int BM = 128;
static constexpr int BK = 32;
static constexpr int THREADS = 512;       // 8 waves: wm(2) x wn(4), wave-tile 64x64
static constexpr int NTILE = MROWS / BM;  // 64
static constexpr size_t PSLICE = (size_t)MROWS * NCOL;  // shorts per partial

DEVFN unsigned short f2bf(float f) {
  union { float f; unsigned u; } x; x.f = f;
  unsigned u = x.u;
  u += 0x7fffu + ((u >> 16) & 1u);   // RNE
  return (unsigned short)(u >> 16);
}

DEVFN float bf2f(unsigned short u) {
  union { unsigned u; float f; } x; x.u = (unsigned)u << 16; return x.f;
}

DEVFN s16x8 pack8(f32x4 v0, f32x4 v1) {
  union { s16x8 v; __hip_bfloat162 h[4]; } pk;
  pk.h[0] = __float22bfloat162_rn(float2{v0[0], v0[1]});
  pk.h[1] = __float22bfloat162_rn(float2{v0[2], v0[3]});
  pk.h[2] = __float22bfloat162_rn(float2{v1[0], v1[1]});
  pk.h[3] = __float22bfloat162_rn(float2{v1[2], v1[3]});
  return pk.v;
}

DEVFN void async16(void* lds, const void* g) {
  __builtin_amdgcn_global_load_lds((const __attribute__((address_space(1))) unsigned*)g,
                                   (__attribute__((address_space(3))) unsigned*)lds,
                                   16, 0, 0);
}

// AP128 A-format: per (128-row tile T, 32-k tile kt) a contiguous 8KB block at
// (T*KT + kt)*4096 shorts, KT = K/32; within, element (row,k) at
// (k>>3)*1024 + row*8 + (k&7).  A fragment (16 consecutive rows, one k-group)
// is a 256B-contiguous run per 16-lane quarter-wave -> conflict-free
// ds_read_b128 (P8-pattern, measured 0 conflicts R4/R7); staging is linear.
// B P8 format: elem(k,j) at ((k>>3)*256 + j)*8 + (k&7) (same property).

// C[M,256] = A[M,K] @ B[K,256]; BM=128, BK=32, 48KB LDS (2 blocks/CU),
// R13 counted-vmcnt discipline: stage(t+1) (3 ops) stays in flight across the
// iteration; 2 raw barriers/iter; never drains mid-loop.
// Output: bf16 P8 partial slice kh (KS-way split-K).
template<int KS>
__global__ __launch_bounds__(THREADS, 4)
void gemm_b(const unsigned short* __restrict__ Ap, int Kfull,
            const unsigned short* __restrict__ Bp8,
            unsigned short* __restrict__ Pout)
{
  __shared__ __align__(16) unsigned short As[2][4096];   // 2 x 8KB
  __shared__ __align__(16) unsigned short Bs[2][8192];   // 2 x 16KB -> 48KB

  const int nwg = NTILE * KS, q = nwg / 8;
  const int logical = (blockIdx.x & 7) * q + (blockIdx.x >> 3);  // XCD-chunked
  const int kh = logical / NTILE;       // KS=8: one kh per XCD
  const int tile = logical % NTILE;
  const int klen = Kfull / KS;
  const int nt = klen / BK;
  const int k0 = kh * klen;
  const int KT = Kfull >> 5;
  const int kt0 = k0 >> 5;
  const int tid = threadIdx.x, lane = tid & 63;
  const int wm = (tid >> 6) >> 2;       // 0..1 : rows wm*64..+64
  const int wn = (tid >> 6) & 3;        // 0..3 : cols wn*64..+64
  const int lr = lane & 15, lg = lane >> 4;

  auto stage = [&](int buf, int t) {    // 3 async ops / thread, all linear
    async16(&As[buf][tid * 8], Ap + ((size_t)tile * KT + kt0 + t) * 4096 + tid * 8);
    const unsigned short* bsrc = Bp8 + (size_t)(k0 + t * BK) * 256 + tid * 8;
    async16(&Bs[buf][tid * 8], bsrc);
    async16(&Bs[buf][4096 + tid * 8], bsrc + 4096);
  };

  f32x4 acc[4][4] = {};

  stage(0, 0);

  int cur = 0;
  for (int t = 0; t < nt; ++t) {
    if (t + 1 < nt) {
      stage(cur ^ 1, t + 1);                 // prefetch stays in flight
      asm volatile("s_waitcnt vmcnt(3)");    // stage(t) landed (3 newer remain)
    } else {
      asm volatile("s_waitcnt vmcnt(0)");    // tail: drain
    }
    __builtin_amdgcn_s_barrier();            // all waves' stage(t) landed
    __builtin_amdgcn_sched_barrier(0);       // pin LDS reads below barrier
    s16x8 af[4], bf[4];
#pragma unroll
    for (int fm = 0; fm < 4; ++fm) {
      const int row = wm * 64 + fm * 16 + lr;
      af[fm] = *(const s16x8*)&As[cur][lg * 1024 + row * 8];
    }
#pragma unroll
    for (int fn = 0; fn < 4; ++fn)
      bf[fn] = *(const s16x8*)&Bs[cur][lg * 2048 + (wn * 64 + fn * 16 + lr) * 8];
#pragma unroll
    for (int fm = 0; fm < 4; ++fm)
#pragma unroll
      for (int fn = 0; fn < 4; ++fn)
        acc[fm][fn] = __builtin_amdgcn_mfma_f32_16x16x32_bf16(af[fm], bf[fn], acc[fm][fn], 0, 0, 0);
    __builtin_amdgcn_s_barrier();            // all waves done reading buf cur
    cur ^= 1;
  }

  // C/D layout: col = lane&15, row = (lane>>4)*4 + reg.  Store bf16 P8.
  unsigned short* dst = Pout + (size_t)kh * PSLICE;
#pragma unroll
  for (int fm = 0; fm < 4; ++fm) {
    const int r0 = tile * BM + wm * 64 + fm * 16 + lg * 4;   // r0&7 in {0,4}
#pragma unroll
    for (int fn = 0; fn < 4; ++fn) {
      const int col = wn * 64 + fn * 16 + lr;
      ushort4 u;
      u.x = f2bf(acc[fm][fn][0]); u.y = f2bf(acc[fm][fn][1]);
      u.z = f2bf(acc[fm][fn][2]); u.w = f2bf(acc[fm][fn][3]);
      *(ushort4*)&dst[((size_t)(r0 >> 3) * 256 + col) * 8 + (r0 & 7)] = u;
    }
  }
}

// ---- stream conversion kernels (memcpy-class) ---------------------------

// f32 row-major [M][K] -> AP128 bf16. One thread per 8 elements. KTSH=log2(K/32).
template<int KTSH>
__global__ void k_cvt_ap(const float* __restrict__ W, unsigned short* __restrict__ outp) {
  const int K = 32 << KTSH;
  size_t gid = (size_t)blockIdx.x * blockDim.x + threadIdx.x;
  const int k8 = (int)(gid & 3);
  const size_t rr = gid >> 2;
  const int row = (int)(rr & 127);
  const size_t bt = rr >> 7;                 // T*KT + kt
  const int kt = (int)(bt & ((1 << KTSH) - 1));
  const size_t T = bt >> KTSH;
  const float* p = W + (T * 128 + row) * (size_t)K + kt * 32 + k8 * 8;
  s16x8 v = pack8(*(const f32x4*)p, *(const f32x4*)(p + 4));
  *(s16x8*)&outp[bt * 4096 + k8 * 1024 + row * 8] = v;
}

// f32 [K][256] -> P8 bf16 (weights)
__global__ void k_convert_p8(const float* __restrict__ W, int K,
                             unsigned short* __restrict__ outp) {
  int tid = blockIdx.x * blockDim.x + threadIdx.x;
  if (tid >= K * NCOL / 4) return;
  int j = tid & (NCOL - 1);
  int i0 = (tid >> 8) << 2;
  unsigned short u[4];
#pragma unroll
  for (int r = 0; r < 4; ++r) u[r] = f2bf(W[(size_t)(i0 + r) * NCOL + j]);
  size_t off = ((size_t)(i0 >> 3) * NCOL + j) * 8 + (i0 & 7);
  *(ushort4*)&outp[off] = make_ushort4(u[0], u[1], u[2], u[3]);
}

// sum NS bf16-P8 partials. One thread per (8-row group, col).
// MODE 0: P8 bf16 out (optional per-row filt); MODE 1: relu -> AP128 bf16
// (K=256, KT=8); MODE 2: f32 row-major out.
template<int NS, int MODE>
__global__ void k_reduce(const unsigned short* __restrict__ P,
                         const float* __restrict__ filt, void* __restrict__ Out) {
  const int tid = blockIdx.x * blockDim.x + threadIdx.x;   // 262144 threads
  const int j = tid & 255;
  const int i8 = tid >> 8;
  const int i0 = i8 * 8;
  const size_t base = ((size_t)i8 * 256 + j) * 8;
  float f[8] = {};
#pragma unroll
  for (int h = 0; h < NS; ++h) {
    s16x8 pv = *(const s16x8*)&P[base + (size_t)h * PSLICE];
#pragma unroll
    for (int r = 0; r < 8; ++r) f[r] += bf2f((unsigned short)pv[r]);
  }
  if constexpr (MODE == 0) {
    if (filt) {
#pragma unroll
      for (int r = 0; r < 8; ++r) f[r] *= filt[i0 + r];
    }
    union { s16x8 v; unsigned short u[8]; } o;
#pragma unroll
    for (int r = 0; r < 8; ++r) o.u[r] = f2bf(f[r]);
    *(s16x8*)&((unsigned short*)Out)[base] = o.v;
  } else if constexpr (MODE == 1) {
    unsigned short* O = (unsigned short*)Out;
#pragma unroll
    for (int r = 0; r < 8; ++r) {
      const int row = i0 + r;
      // AP128, K=256 (KT=8): block (row>>7)*8 + (j>>5)
      O[((size_t)(row >> 7) * 8 + (j >> 5)) * 4096 + ((j >> 3) & 3) * 1024
        + (row & 127) * 8 + (j & 7)] = f2bf(fmaxf(f[r], 0.f));
    }
  } else {
    float* O = (float*)Out;
#pragma unroll
    for (int r = 0; r < 8; ++r)
      O[(size_t)(i0 + r) * NCOL + j] = f[r];
  }
}

extern "C" void kernel_launch(void* const* d_in, const int* in_sizes, int n_in,
                              void* d_out, int out_size, void* d_ws, size_t ws_size,
                              hipStream_t stream) {
  const float* input = (const float*)d_in[0];
  const float* Wv    = (const float*)d_in[1];
  const float* Winv  = (const float*)d_in[2];
  const float* W1    = (const float*)d_in[3];
  const float* W2    = (const float*)d_in[4];
  const float* f1    = (const float*)d_in[5];
  const float* f2    = (const float*)d_in[6];
  float* out = (float*)d_out;

  char* ws = (char*)d_ws;
  unsigned short* WvB   = (unsigned short*)(ws);                 // 128MB AP128
  unsigned short* WinvB = (unsigned short*)(ws + 0x8000000);     // 128MB AP128
  unsigned short* inB   = (unsigned short*)(ws + 0x10000000);    // 8MB AP128
  unsigned short* partB = (unsigned short*)(ws + 0x10800000);    // 32MB (8 x bf16 P8)
  unsigned short* t1p   = (unsigned short*)(ws + 0x12800000);    // 4MB each, P8
  unsigned short* s1p   = (unsigned short*)(ws + 0x12C00000);
  unsigned short* t2p   = (unsigned short*)(ws + 0x13000000);
  unsigned short* s2p   = (unsigned short*)(ws + 0x13400000);
  unsigned short* h1b   = (unsigned short*)(ws + 0x13800000);    // 4MB AP128
  unsigned short* W1p   = (unsigned short*)(ws + 0x13C00000);    // 256KB
  unsigned short* W2p   = (unsigned short*)(ws + 0x13C40000);    // 128KB

  dim3 gT(THREADS);
  dim3 g8(NTILE * 8), g2(NTILE * 2);                   // 512 / 128 WGs
  dim3 rT(256), rG(MROWS * NCOL / 8 / 256);            // 1024 WGs

  // stream converts (memcpy-class)
  k_cvt_ap<8><<<dim3(32768), rT, 0, stream>>>(Wv, WvB);
  k_cvt_ap<8><<<dim3(32768), rT, 0, stream>>>(Winv, WinvB);
  k_cvt_ap<4><<<dim3(2048),  rT, 0, stream>>>(input, inB);
  k_convert_p8<<<dim3(128), rT, 0, stream>>>(W1, 512, W1p);
  k_convert_p8<<<dim3(64),  rT, 0, stream>>>(W2, 256, W2p);

  // t1 = input @ W1                  (K=512, KS=2)
  gemm_b<2><<<g2, gT, 0, stream>>>(inB, 512, W1p, partB);
  k_reduce<2, 0><<<rG, rT, 0, stream>>>(partB, nullptr, t1p);
  // s1 = diag(f1).(Winv @ t1)
  gemm_b<8><<<g8, gT, 0, stream>>>(WinvB, 8192, t1p, partB);
  k_reduce<8, 0><<<rG, rT, 0, stream>>>(partB, f1, s1p);
  // h1 = relu(Wv @ s1) -> AP128
  gemm_b<8><<<g8, gT, 0, stream>>>(WvB, 8192, s1p, partB);
  k_reduce<8, 1><<<rG, rT, 0, stream>>>(partB, nullptr, h1b);
  // t2 = h1 @ W2                     (K=256, KS=2)
  gemm_b<2><<<g2, gT, 0, stream>>>(h1b, 256, W2p, partB);
  k_reduce<2, 0><<<rG, rT, 0, stream>>>(partB, nullptr, t2p);
  // s2 = diag(f2).(Winv @ t2)
  gemm_b<8><<<g8, gT, 0, stream>>>(WinvB, 8192, t2p, partB);
  k_reduce<8, 0><<<rG, rT, 0, stream>>>(partB, f2, s2p);
  // out = Wv @ s2
  gemm_b<8><<<g8, gT, 0, stream>>>(WvB, 8192, s2p, partB);
  k_reduce<8, 2><<<rG, rT, 0, stream>>>(partB, nullptr, out);
}

// Round 19
// 364.151 us; speedup vs baseline: 1.3152x; 1.0923x over previous
//
#include <hip/hip_runtime.h>
#include <hip/hip_bf16.h>

using f32x4 = __attribute__((ext_vector_type(4))) float;
using s16x8 = __attribute__((ext_vector_type(8))) short;

#define DEVFN static __device__ __forceinline__

static constexpr int NCOL = 256;
static constexpr int MROWS = 8192;
static constexpr int BM = 64;
static constexpr int BK = 64;
static constexpr int THREADS = 512;       // 8 waves: wm(2) x wn(4)
static constexpr int NTILE = MROWS / BM;  // 128
static constexpr size_t PSLICE = (size_t)MROWS * NCOL;  // shorts per partial

DEVFN unsigned short f2bf(float f) {
  union { float f; unsigned u; } x; x.f = f;
  unsigned u = x.u;
  u += 0x7fffu + ((u >> 16) & 1u);   // RNE
  return (unsigned short)(u >> 16);
}

DEVFN float bf2f(unsigned short u) {
  union { unsigned u; float f; } x; x.u = (unsigned)u << 16; return x.f;
}

DEVFN s16x8 pack8(f32x4 v0, f32x4 v1) {
  union { s16x8 v; __hip_bfloat162 h[4]; } pk;
  pk.h[0] = __float22bfloat162_rn(float2{v0[0], v0[1]});
  pk.h[1] = __float22bfloat162_rn(float2{v0[2], v0[3]});
  pk.h[2] = __float22bfloat162_rn(float2{v1[0], v1[1]});
  pk.h[3] = __float22bfloat162_rn(float2{v1[2], v1[3]});
  return pk.v;
}

DEVFN void async16(void* lds, const void* g) {
  __builtin_amdgcn_global_load_lds((const __attribute__((address_space(1))) unsigned*)g,
                                   (__attribute__((address_space(3))) unsigned*)lds,
                                   16, 0, 0);
}

// AP64 A-format: per (64-row tile T, 64-k tile kt) a contiguous 8KB block at
// (T*KT + kt)*4096 shorts, KT = K/64; within, element (row,k) at
// (k>>3)*512 + row*8 + (k&7).  A fragment (16 consecutive rows, one k-group)
// is 128B contiguous per 16-lane quarter-wave -> conflict-free ds_read_b128;
// staging is linear (tid*16B).
// B P8 format: elem(k,j) at ((k>>3)*256 + j)*8 + (k&7).

// C[M,256] = A[M,K] @ B[K,256]; R13 champion skeleton (BM=64/BK=64, 80KB LDS,
// 2 blocks/CU, counted-vmcnt, 2 raw barriers/iter).
//  AF32: A is f32 row-major, reg-staged (loads issued FIRST each iter so the
//        pack8 dep-wait is vmcnt(4), leaving B(t+1) in flight), cvt once,
//        ds_write + (WB) coalesced bf16 writeback to Awb in AP64.
//  !AF32: A is AP64 bf16 via global_load_lds (1 op).
// Output: bf16 P8 partial slice kh (KS==1 -> directly next GEMM's B operand).
template<bool AF32, bool WB, int KS>
__global__ __launch_bounds__(THREADS, 4)
void gemm_f(const void* __restrict__ Aany, int Kfull,
            const unsigned short* __restrict__ Bp8,
            unsigned short* __restrict__ Pout,
            unsigned short* __restrict__ Awb)
{
  __shared__ __align__(16) unsigned short As[2][4096];    // 2 x 8KB
  __shared__ __align__(16) unsigned short Bs[2][16384];   // 2 x 32KB -> 80KB

  const int nwg = NTILE * KS, q = nwg / 8;
  const int logical = (blockIdx.x & 7) * q + (blockIdx.x >> 3);  // XCD-chunked
  const int kh = logical / NTILE;
  const int tile = logical % NTILE;
  const int klen = Kfull / KS;
  const int nt = klen / BK;
  const int k0 = kh * klen;
  const int KT = Kfull >> 6;
  const int kt0 = k0 >> 6;
  const int tid = threadIdx.x, lane = tid & 63;
  const int wm = (tid >> 6) >> 2;       // 0..1 : rows wm*32..+32
  const int wn = (tid >> 6) & 3;        // 0..3 : cols wn*64..+64
  const int lr = lane & 15, lg = lane >> 4;
  const int srow = tid >> 3, sk8 = tid & 7;   // AF32 stage coords

  auto stageB = [&](int buf, int t) {   // 4 async ops
    const unsigned short* b = Bp8 + (size_t)(k0 + t * BK) * 256 + tid * 8;
#pragma unroll
    for (int o = 0; o < 4; ++o)
      async16(&Bs[buf][o * 4096 + tid * 8], b + o * 4096);
  };
  auto stageA_bf = [&](int buf, int t) { // 1 async op
    async16(&As[buf][tid * 8],
            (const unsigned short*)Aany + ((size_t)tile * KT + kt0 + t) * 4096 + tid * 8);
  };

  f32x4 ra0, ra1;
  auto loadA = [&](int t) {             // 2 loads, 32B contiguous / thread
    const float* p = (const float*)Aany + (size_t)(tile * BM + srow) * Kfull
                   + k0 + t * BK + sk8 * 8;
    ra0 = *(const f32x4*)p; ra1 = *(const f32x4*)(p + 4);
  };
  auto putA = [&](int buf, int t) {     // cvt once + ds_write (+WB store)
    s16x8 v = pack8(ra0, ra1);
    *(s16x8*)&As[buf][sk8 * 512 + srow * 8] = v;
    if constexpr (WB)
      *(s16x8*)&Awb[((size_t)tile * KT + kt0 + t) * 4096 + sk8 * 512 + srow * 8] = v;
  };

  f32x4 acc[2][4] = {};

  if constexpr (AF32) {
    loadA(0); stageB(0, 0); putA(0, 0);
    asm volatile("s_waitcnt lgkmcnt(0)");   // prologue ds_write visible
  } else {
    stageA_bf(0, 0); stageB(0, 0);
  }

  int cur = 0;
  for (int t = 0; t < nt; ++t) {
    if constexpr (AF32) {
      if (t + 1 < nt) {
        loadA(t + 1);                        // A loads FIRST (older than B)
        stageB(cur ^ 1, t + 1);              // B prefetch stays in flight
        if constexpr (WB) asm volatile("s_waitcnt vmcnt(7)");  // B(t) landed; store+A+B(t+1) remain
        else              asm volatile("s_waitcnt vmcnt(6)");
      } else {
        asm volatile("s_waitcnt vmcnt(0)");  // tail: drain
      }
    } else {
      if (t + 1 < nt) {
        stageA_bf(cur ^ 1, t + 1); stageB(cur ^ 1, t + 1);
        asm volatile("s_waitcnt vmcnt(5)");  // stage(t) landed (5 newer remain)
      } else {
        asm volatile("s_waitcnt vmcnt(0)");
      }
    }
    __builtin_amdgcn_s_barrier();            // all waves' stage(t) landed
    __builtin_amdgcn_sched_barrier(0);       // pin LDS reads below barrier
#pragma unroll
    for (int s = 0; s < 2; ++s) {
      const int kc = s * 4 + lg;        // 0..7
      s16x8 a0 = *(const s16x8*)&As[cur][kc * 512 + (wm * 32 + lr) * 8];
      s16x8 a1 = *(const s16x8*)&As[cur][kc * 512 + (wm * 32 + 16 + lr) * 8];
#pragma unroll
      for (int fn = 0; fn < 4; ++fn) {
        s16x8 b = *(const s16x8*)&Bs[cur][kc * 2048 + (wn * 64 + fn * 16 + lr) * 8];
        acc[0][fn] = __builtin_amdgcn_mfma_f32_16x16x32_bf16(a0, b, acc[0][fn], 0, 0, 0);
        acc[1][fn] = __builtin_amdgcn_mfma_f32_16x16x32_bf16(a1, b, acc[1][fn], 0, 0, 0);
      }
    }
    if constexpr (AF32) {
      __builtin_amdgcn_sched_barrier(0);     // keep putA BELOW the MFMAs
      if (t + 1 < nt) putA(cur ^ 1, t + 1);  // compiler waits vmcnt(4): A only
      asm volatile("s_waitcnt lgkmcnt(0)");  // ds_write visible before barrier
      __builtin_amdgcn_sched_barrier(0);
    }
    __builtin_amdgcn_s_barrier();            // all waves done with buf cur
    cur ^= 1;
  }

  // C/D layout: col = lane&15, row = (lane>>4)*4 + reg.  Store bf16 P8.
  unsigned short* dst = Pout + (size_t)kh * PSLICE;
#pragma unroll
  for (int fm = 0; fm < 2; ++fm) {
    const int r0 = tile * BM + wm * 32 + fm * 16 + lg * 4;   // r0&7 in {0,4}
#pragma unroll
    for (int fn = 0; fn < 4; ++fn) {
      const int col = wn * 64 + fn * 16 + lr;
      ushort4 u;
      u.x = f2bf(acc[fm][fn][0]); u.y = f2bf(acc[fm][fn][1]);
      u.z = f2bf(acc[fm][fn][2]); u.w = f2bf(acc[fm][fn][3]);
      *(ushort4*)&dst[((size_t)(r0 >> 3) * 256 + col) * 8 + (r0 & 7)] = u;
    }
  }
}

// ---- small conversion / reduce kernels ---------------------------------

// f32 [K][256] -> P8 bf16 (weights)
__global__ void k_convert_p8(const float* __restrict__ W, int K,
                             unsigned short* __restrict__ outp) {
  int tid = blockIdx.x * blockDim.x + threadIdx.x;
  if (tid >= K * NCOL / 4) return;
  int j = tid & (NCOL - 1);
  int i0 = (tid >> 8) << 2;
  unsigned short u[4];
#pragma unroll
  for (int r = 0; r < 4; ++r) u[r] = f2bf(W[(size_t)(i0 + r) * NCOL + j]);
  size_t off = ((size_t)(i0 >> 3) * NCOL + j) * 8 + (i0 & 7);
  *(ushort4*)&outp[off] = make_ushort4(u[0], u[1], u[2], u[3]);
}

// sum 4 bf16-P8 partials. One thread per (8-row group, col).
// MODE 0: P8 bf16 out (optional per-row filt); MODE 1: relu -> AP64 bf16
// (K=256, KT=4); MODE 2: f32 row-major out.
template<int MODE>
__global__ void k_reduce(const unsigned short* __restrict__ P,
                         const float* __restrict__ filt, void* __restrict__ Out) {
  const int tid = blockIdx.x * blockDim.x + threadIdx.x;   // 262144 threads
  const int j = tid & 255;
  const int i8 = tid >> 8;
  const int i0 = i8 * 8;
  const size_t base = ((size_t)i8 * 256 + j) * 8;
  float f[8] = {};
#pragma unroll
  for (int h = 0; h < 4; ++h) {
    s16x8 pv = *(const s16x8*)&P[base + (size_t)h * PSLICE];
#pragma unroll
    for (int r = 0; r < 8; ++r) f[r] += bf2f((unsigned short)pv[r]);
  }
  if constexpr (MODE == 0) {
    if (filt) {
#pragma unroll
      for (int r = 0; r < 8; ++r) f[r] *= filt[i0 + r];
    }
    union { s16x8 v; unsigned short u[8]; } o;
#pragma unroll
    for (int r = 0; r < 8; ++r) o.u[r] = f2bf(f[r]);
    *(s16x8*)&((unsigned short*)Out)[base] = o.v;
  } else if constexpr (MODE == 1) {
    unsigned short* O = (unsigned short*)Out;
#pragma unroll
    for (int r = 0; r < 8; ++r) {
      const int row = i0 + r;
      // AP64, K=256 (KT=4): block (row>>6)*4 + (j>>6); elem k-group (j>>3)&7
      O[((size_t)(row >> 6) * 4 + (j >> 6)) * 4096 + ((j >> 3) & 7) * 512
        + (row & 63) * 8 + (j & 7)] = f2bf(fmaxf(f[r], 0.f));
    }
  } else {
    float* O = (float*)Out;
#pragma unroll
    for (int r = 0; r < 8; ++r)
      O[(size_t)(i0 + r) * NCOL + j] = f[r];
  }
}

extern "C" void kernel_launch(void* const* d_in, const int* in_sizes, int n_in,
                              void* d_out, int out_size, void* d_ws, size_t ws_size,
                              hipStream_t stream) {
  const float* input = (const float*)d_in[0];
  const float* Wv    = (const float*)d_in[1];
  const float* Winv  = (const float*)d_in[2];
  const float* W1    = (const float*)d_in[3];
  const float* W2    = (const float*)d_in[4];
  const float* f1    = (const float*)d_in[5];
  const float* f2    = (const float*)d_in[6];
  float* out = (float*)d_out;

  char* ws = (char*)d_ws;
  unsigned short* WvB   = (unsigned short*)(ws);                 // 128MB AP64
  unsigned short* WinvB = (unsigned short*)(ws + 0x8000000);     // 128MB AP64
  unsigned short* partB = (unsigned short*)(ws + 0x10000000);    // 16MB (4 x bf16 P8)
  unsigned short* t1p   = (unsigned short*)(ws + 0x11000000);    // 4MB each, P8
  unsigned short* s1p   = (unsigned short*)(ws + 0x11400000);
  unsigned short* t2p   = (unsigned short*)(ws + 0x11800000);
  unsigned short* s2p   = (unsigned short*)(ws + 0x11C00000);
  unsigned short* h1b   = (unsigned short*)(ws + 0x12000000);    // 4MB AP64
  unsigned short* W1p   = (unsigned short*)(ws + 0x12400000);    // 256KB
  unsigned short* W2p   = (unsigned short*)(ws + 0x12440000);    // 128KB

  dim3 gT(THREADS);
  dim3 g4(NTILE * 4), g1(NTILE);                       // 512 / 128 WGs
  dim3 rT(256), rG(MROWS * NCOL / 8 / 256);            // 1024 WGs

  k_convert_p8<<<dim3(128), rT, 0, stream>>>(W1, 512, W1p);
  k_convert_p8<<<dim3(64),  rT, 0, stream>>>(W2, 256, W2p);

  // t1 = input @ W1             (fused f32 A, K=512, KS=1 -> direct P8)
  gemm_f<true, false, 1><<<g1, gT, 0, stream>>>(
      (const void*)input, 512, W1p, t1p, nullptr);
  // s1 = diag(f1).(Winv @ t1)   (fused f32 A + bf16 writeback)
  gemm_f<true, true, 4><<<g4, gT, 0, stream>>>(
      (const void*)Winv, 8192, t1p, partB, WinvB);
  k_reduce<0><<<rG, rT, 0, stream>>>(partB, f1, s1p);
  // h1 = relu(Wv @ s1) -> AP64  (fused f32 A + bf16 writeback)
  gemm_f<true, true, 4><<<g4, gT, 0, stream>>>(
      (const void*)Wv, 8192, s1p, partB, WvB);
  k_reduce<1><<<rG, rT, 0, stream>>>(partB, nullptr, h1b);
  // t2 = h1 @ W2                (AP64 bf16 A, K=256, KS=1 -> direct P8)
  gemm_f<false, false, 1><<<g1, gT, 0, stream>>>(
      (const void*)h1b, 256, W2p, t2p, nullptr);
  // s2 = diag(f2).(Winv @ t2)   (AP64 bf16 copy)
  gemm_f<false, false, 4><<<g4, gT, 0, stream>>>(
      (const void*)WinvB, 8192, t2p, partB, nullptr);
  k_reduce<0><<<rG, rT, 0, stream>>>(partB, f2, s2p);
  // out = Wv @ s2               (AP64 bf16 copy, f32 out)
  gemm_f<false, false, 4><<<g4, gT, 0, stream>>>(
      (const void*)WvB, 8192, s2p, partB, nullptr);
  k_reduce<2><<<rG, rT, 0, stream>>>(partB, nullptr, out);
}

// Round 20
// 362.334 us; speedup vs baseline: 1.3218x; 1.0050x over previous
//
#include <hip/hip_runtime.h>
#include <hip/hip_bf16.h>

using f32x4 = __attribute__((ext_vector_type(4))) float;
using s16x8 = __attribute__((ext_vector_type(8))) short;

#define DEVFN static __device__ __forceinline__

static constexpr int NCOL = 256;
static constexpr int MROWS = 8192;
static constexpr int BM = 64;
static constexpr int BK = 64;
static constexpr int THREADS = 512;       // 8 waves: wm(2) x wn(4)
static constexpr int NTILE = MROWS / BM;  // 128
static constexpr size_t PSLICE = (size_t)MROWS * NCOL;  // shorts per partial

DEVFN unsigned short f2bf(float f) {
  union { float f; unsigned u; } x; x.f = f;
  unsigned u = x.u;
  u += 0x7fffu + ((u >> 16) & 1u);   // RNE
  return (unsigned short)(u >> 16);
}

DEVFN float bf2f(unsigned short u) {
  union { unsigned u; float f; } x; x.u = (unsigned)u << 16; return x.f;
}

DEVFN s16x8 pack8(f32x4 v0, f32x4 v1) {
  union { s16x8 v; __hip_bfloat162 h[4]; } pk;
  pk.h[0] = __float22bfloat162_rn(float2{v0[0], v0[1]});
  pk.h[1] = __float22bfloat162_rn(float2{v0[2], v0[3]});
  pk.h[2] = __float22bfloat162_rn(float2{v1[0], v1[1]});
  pk.h[3] = __float22bfloat162_rn(float2{v1[2], v1[3]});
  return pk.v;
}

DEVFN void async16(void* lds, const void* g) {
  __builtin_amdgcn_global_load_lds((const __attribute__((address_space(1))) unsigned*)g,
                                   (__attribute__((address_space(3))) unsigned*)lds,
                                   16, 0, 0);
}

// AP64 A-format: per (64-row tile T, 64-k tile kt) a contiguous 8KB block at
// (T*KT + kt)*4096 shorts, KT = K/64; within, element (row,k) at
// (k>>3)*512 + row*8 + (k&7).  A fragment (16 consecutive rows, one k-group)
// is 128B contiguous per 16-lane quarter-wave -> conflict-free ds_read_b128;
// staging is linear (tid*16B).
// B P8 format: elem(k,j) at ((k>>3)*256 + j)*8 + (k&7).

// C[M,256] = A[M,K] @ B[K,256]; champion skeleton (BM=64/BK=64, 80KB LDS,
// 2 blocks/CU, counted-vmcnt, 2 raw barriers/iter) + T5 setprio on MFMAs.
//  AF32: A f32 row-major, reg-staged (loads FIRST each iter), cvt once,
//        ds_write + (WB) coalesced bf16 writeback to Awb in AP64.
//  !AF32: A AP64 bf16 via global_load_lds (1 op).
// Output: bf16 P8 partial slice kh (KS==1 -> directly next GEMM's B operand).
template<bool AF32, bool WB, int KS>
__global__ __launch_bounds__(THREADS, 4)
void gemm_f(const void* __restrict__ Aany, int Kfull,
            const unsigned short* __restrict__ Bp8,
            unsigned short* __restrict__ Pout,
            unsigned short* __restrict__ Awb)
{
  __shared__ __align__(16) unsigned short As[2][4096];    // 2 x 8KB
  __shared__ __align__(16) unsigned short Bs[2][16384];   // 2 x 32KB -> 80KB

  const int nwg = NTILE * KS, q = nwg / 8;
  const int logical = (blockIdx.x & 7) * q + (blockIdx.x >> 3);  // XCD-chunked
  const int kh = logical / NTILE;
  const int tile = logical % NTILE;
  const int klen = Kfull / KS;
  const int nt = klen / BK;
  const int k0 = kh * klen;
  const int KT = Kfull >> 6;
  const int kt0 = k0 >> 6;
  const int tid = threadIdx.x, lane = tid & 63;
  const int wm = (tid >> 6) >> 2;       // 0..1 : rows wm*32..+32
  const int wn = (tid >> 6) & 3;        // 0..3 : cols wn*64..+64
  const int lr = lane & 15, lg = lane >> 4;
  const int srow = tid >> 3, sk8 = tid & 7;   // AF32 stage coords

  auto stageB = [&](int buf, int t) {   // 4 async ops
    const unsigned short* b = Bp8 + (size_t)(k0 + t * BK) * 256 + tid * 8;
#pragma unroll
    for (int o = 0; o < 4; ++o)
      async16(&Bs[buf][o * 4096 + tid * 8], b + o * 4096);
  };
  auto stageA_bf = [&](int buf, int t) { // 1 async op
    async16(&As[buf][tid * 8],
            (const unsigned short*)Aany + ((size_t)tile * KT + kt0 + t) * 4096 + tid * 8);
  };

  f32x4 ra0, ra1;
  auto loadA = [&](int t) {             // 2 loads, 32B contiguous / thread
    const float* p = (const float*)Aany + (size_t)(tile * BM + srow) * Kfull
                   + k0 + t * BK + sk8 * 8;
    ra0 = *(const f32x4*)p; ra1 = *(const f32x4*)(p + 4);
  };
  auto putA = [&](int buf, int t) {     // cvt once + ds_write (+WB store)
    s16x8 v = pack8(ra0, ra1);
    *(s16x8*)&As[buf][sk8 * 512 + srow * 8] = v;
    if constexpr (WB)
      *(s16x8*)&Awb[((size_t)tile * KT + kt0 + t) * 4096 + sk8 * 512 + srow * 8] = v;
  };

  f32x4 acc[2][4] = {};

  if constexpr (AF32) {
    loadA(0); stageB(0, 0); putA(0, 0);
    asm volatile("s_waitcnt lgkmcnt(0)");   // prologue ds_write visible
  } else {
    stageA_bf(0, 0); stageB(0, 0);
  }

  int cur = 0;
  for (int t = 0; t < nt; ++t) {
    if constexpr (AF32) {
      if (t + 1 < nt) {
        loadA(t + 1);                        // A loads FIRST (older than B)
        stageB(cur ^ 1, t + 1);              // B prefetch stays in flight
        if constexpr (WB) asm volatile("s_waitcnt vmcnt(7)");  // B(t) landed
        else              asm volatile("s_waitcnt vmcnt(6)");
      } else {
        asm volatile("s_waitcnt vmcnt(0)");  // tail: drain
      }
    } else {
      if (t + 1 < nt) {
        stageA_bf(cur ^ 1, t + 1); stageB(cur ^ 1, t + 1);
        asm volatile("s_waitcnt vmcnt(5)");  // stage(t) landed (5 newer remain)
      } else {
        asm volatile("s_waitcnt vmcnt(0)");
      }
    }
    __builtin_amdgcn_s_barrier();            // all waves' stage(t) landed
    __builtin_amdgcn_sched_barrier(0);       // pin LDS reads below barrier
    __builtin_amdgcn_s_setprio(1);           // T5: favor MFMA-phase waves
#pragma unroll
    for (int s = 0; s < 2; ++s) {
      const int kc = s * 4 + lg;        // 0..7
      s16x8 a0 = *(const s16x8*)&As[cur][kc * 512 + (wm * 32 + lr) * 8];
      s16x8 a1 = *(const s16x8*)&As[cur][kc * 512 + (wm * 32 + 16 + lr) * 8];
#pragma unroll
      for (int fn = 0; fn < 4; ++fn) {
        s16x8 b = *(const s16x8*)&Bs[cur][kc * 2048 + (wn * 64 + fn * 16 + lr) * 8];
        acc[0][fn] = __builtin_amdgcn_mfma_f32_16x16x32_bf16(a0, b, acc[0][fn], 0, 0, 0);
        acc[1][fn] = __builtin_amdgcn_mfma_f32_16x16x32_bf16(a1, b, acc[1][fn], 0, 0, 0);
      }
    }
    __builtin_amdgcn_s_setprio(0);
    if constexpr (AF32) {
      __builtin_amdgcn_sched_barrier(0);     // keep putA BELOW the MFMAs
      if (t + 1 < nt) putA(cur ^ 1, t + 1);  // compiler waits vmcnt: A only
      asm volatile("s_waitcnt lgkmcnt(0)");  // ds_write visible before barrier
      __builtin_amdgcn_sched_barrier(0);
    }
    __builtin_amdgcn_s_barrier();            // all waves done with buf cur
    cur ^= 1;
  }

  // C/D layout: col = lane&15, row = (lane>>4)*4 + reg.  Store bf16 P8.
  unsigned short* dst = Pout + (size_t)kh * PSLICE;
#pragma unroll
  for (int fm = 0; fm < 2; ++fm) {
    const int r0 = tile * BM + wm * 32 + fm * 16 + lg * 4;   // r0&7 in {0,4}
#pragma unroll
    for (int fn = 0; fn < 4; ++fn) {
      const int col = wn * 64 + fn * 16 + lr;
      ushort4 u;
      u.x = f2bf(acc[fm][fn][0]); u.y = f2bf(acc[fm][fn][1]);
      u.z = f2bf(acc[fm][fn][2]); u.w = f2bf(acc[fm][fn][3]);
      *(ushort4*)&dst[((size_t)(r0 >> 3) * 256 + col) * 8 + (r0 & 7)] = u;
    }
  }
}

// ---- small conversion / reduce kernels ---------------------------------

// Both weight matrices -> P8 bf16 in one launch.
// Blocks [0,128): W1 (K=512); blocks [128,192): W2 (K=256).
__global__ void k_convert_w(const float* __restrict__ W1, const float* __restrict__ W2,
                            unsigned short* __restrict__ W1p,
                            unsigned short* __restrict__ W2p) {
  const bool is2 = blockIdx.x >= 128;
  const float* W = is2 ? W2 : W1;
  unsigned short* outp = is2 ? W2p : W1p;
  int tid = (is2 ? (blockIdx.x - 128) : blockIdx.x) * blockDim.x + threadIdx.x;
  int j = tid & (NCOL - 1);
  int i0 = (tid >> 8) << 2;
  unsigned short u[4];
#pragma unroll
  for (int r = 0; r < 4; ++r) u[r] = f2bf(W[(size_t)(i0 + r) * NCOL + j]);
  size_t off = ((size_t)(i0 >> 3) * NCOL + j) * 8 + (i0 & 7);
  *(ushort4*)&outp[off] = make_ushort4(u[0], u[1], u[2], u[3]);
}

// sum 4 bf16-P8 partials. One thread per (8-row group, col).
// MODE 0: P8 bf16 out (optional per-row filt); MODE 1: relu -> AP64 bf16
// (K=256, KT=4); MODE 2: f32 row-major out.
template<int MODE>
__global__ void k_reduce(const unsigned short* __restrict__ P,
                         const float* __restrict__ filt, void* __restrict__ Out) {
  const int tid = blockIdx.x * blockDim.x + threadIdx.x;   // 262144 threads
  const int j = tid & 255;
  const int i8 = tid >> 8;
  const int i0 = i8 * 8;
  const size_t base = ((size_t)i8 * 256 + j) * 8;
  float f[8] = {};
#pragma unroll
  for (int h = 0; h < 4; ++h) {
    s16x8 pv = *(const s16x8*)&P[base + (size_t)h * PSLICE];
#pragma unroll
    for (int r = 0; r < 8; ++r) f[r] += bf2f((unsigned short)pv[r]);
  }
  if constexpr (MODE == 0) {
    if (filt) {
#pragma unroll
      for (int r = 0; r < 8; ++r) f[r] *= filt[i0 + r];
    }
    union { s16x8 v; unsigned short u[8]; } o;
#pragma unroll
    for (int r = 0; r < 8; ++r) o.u[r] = f2bf(f[r]);
    *(s16x8*)&((unsigned short*)Out)[base] = o.v;
  } else if constexpr (MODE == 1) {
    unsigned short* O = (unsigned short*)Out;
#pragma unroll
    for (int r = 0; r < 8; ++r) {
      const int row = i0 + r;
      // AP64, K=256 (KT=4): block (row>>6)*4 + (j>>6); elem k-group (j>>3)&7
      O[((size_t)(row >> 6) * 4 + (j >> 6)) * 4096 + ((j >> 3) & 7) * 512
        + (row & 63) * 8 + (j & 7)] = f2bf(fmaxf(f[r], 0.f));
    }
  } else {
    float* O = (float*)Out;
#pragma unroll
    for (int r = 0; r < 8; ++r)
      O[(size_t)(i0 + r) * NCOL + j] = f[r];
  }
}

extern "C" void kernel_launch(void* const* d_in, const int* in_sizes, int n_in,
                              void* d_out, int out_size, void* d_ws, size_t ws_size,
                              hipStream_t stream) {
  const float* input = (const float*)d_in[0];
  const float* Wv    = (const float*)d_in[1];
  const float* Winv  = (const float*)d_in[2];
  const float* W1    = (const float*)d_in[3];
  const float* W2    = (const float*)d_in[4];
  const float* f1    = (const float*)d_in[5];
  const float* f2    = (const float*)d_in[6];
  float* out = (float*)d_out;

  char* ws = (char*)d_ws;
  unsigned short* WvB   = (unsigned short*)(ws);                 // 128MB AP64
  unsigned short* WinvB = (unsigned short*)(ws + 0x8000000);     // 128MB AP64
  unsigned short* partB = (unsigned short*)(ws + 0x10000000);    // 16MB (4 x bf16 P8)
  unsigned short* t1p   = (unsigned short*)(ws + 0x11000000);    // 4MB each, P8
  unsigned short* s1p   = (unsigned short*)(ws + 0x11400000);
  unsigned short* t2p   = (unsigned short*)(ws + 0x11800000);
  unsigned short* s2p   = (unsigned short*)(ws + 0x11C00000);
  unsigned short* h1b   = (unsigned short*)(ws + 0x12000000);    // 4MB AP64
  unsigned short* W1p   = (unsigned short*)(ws + 0x12400000);    // 256KB
  unsigned short* W2p   = (unsigned short*)(ws + 0x12440000);    // 128KB

  dim3 gT(THREADS);
  dim3 g4(NTILE * 4), g1(NTILE);                       // 512 / 128 WGs
  dim3 rT(256), rG(MROWS * NCOL / 8 / 256);            // 1024 WGs

  k_convert_w<<<dim3(192), rT, 0, stream>>>(W1, W2, W1p, W2p);

  // t1 = input @ W1             (fused f32 A, K=512, KS=1 -> direct P8)
  gemm_f<true, false, 1><<<g1, gT, 0, stream>>>(
      (const void*)input, 512, W1p, t1p, nullptr);
  // s1 = diag(f1).(Winv @ t1)   (fused f32 A + bf16 writeback)
  gemm_f<true, true, 4><<<g4, gT, 0, stream>>>(
      (const void*)Winv, 8192, t1p, partB, WinvB);
  k_reduce<0><<<rG, rT, 0, stream>>>(partB, f1, s1p);
  // h1 = relu(Wv @ s1) -> AP64  (fused f32 A + bf16 writeback)
  gemm_f<true, true, 4><<<g4, gT, 0, stream>>>(
      (const void*)Wv, 8192, s1p, partB, WvB);
  k_reduce<1><<<rG, rT, 0, stream>>>(partB, nullptr, h1b);
  // t2 = h1 @ W2                (AP64 bf16 A, K=256, KS=1 -> direct P8)
  gemm_f<false, false, 1><<<g1, gT, 0, stream>>>(
      (const void*)h1b, 256, W2p, t2p, nullptr);
  // s2 = diag(f2).(Winv @ t2)   (AP64 bf16 copy)
  gemm_f<false, false, 4><<<g4, gT, 0, stream>>>(
      (const void*)WinvB, 8192, t2p, partB, nullptr);
  k_reduce<0><<<rG, rT, 0, stream>>>(partB, f2, s2p);
  // out = Wv @ s2               (AP64 bf16 copy, f32 out)
  gemm_f<false, false, 4><<<g4, gT, 0, stream>>>(
      (const void*)WvB, 8192, s2p, partB, nullptr);
  k_reduce<2><<<rG, rT, 0, stream>>>(partB, nullptr, out);
}